// Round 4
// baseline (265.187 us; speedup 1.0000x reference)
//
#include <hip/hip_runtime.h>
#include <math.h>

#define S 4096
#define CNUM 128
#define BATCH 4
#define MTOT (BATCH * S)
#define SCLOG2E 0.36067376022224085f   // 0.25 * log2(e): scores in log2 domain
#define EPSLN 1e-5f
#define KSPLIT 8                        // k-range split for fused attn partials
#define QSPLIT 4                        // q-range split for column-sum pass

typedef __attribute__((ext_vector_type(8))) short bf16x8;
typedef __attribute__((ext_vector_type(4))) float f32x4;
typedef __attribute__((ext_vector_type(4))) unsigned int u32x4;

__device__ __forceinline__ float gelu_exact(float x) {
    return 0.5f * x * (1.0f + erff(x * 0.7071067811865476f));
}

__device__ __forceinline__ unsigned short f2b(float f) {
    union { float f; unsigned int u; } v; v.f = f;
    unsigned int r = (v.u + 0x7FFFu + ((v.u >> 16) & 1u)) >> 16;
    return (unsigned short)r;
}
// cheap round-half-up for positive values (2 ops)
__device__ __forceinline__ unsigned short f2b_ru(float f) {
    return (unsigned short)((__float_as_uint(f) + 0x8000u) >> 16);
}
__device__ __forceinline__ float b2f(unsigned short u) {
    return __uint_as_float((unsigned)u << 16);
}

// async 16B global->LDS (direct DMA, no VGPR round trip)
__device__ __forceinline__ void gl_lds16(const void* g, void* l) {
    __builtin_amdgcn_global_load_lds(
        (__attribute__((address_space(1))) void*)g,
        (__attribute__((address_space(3))) void*)l, 16, 0, 0);
}

// ---------------- transpose [B,C,S] -> [B,S,C]: t fp32 (residual), xlh bf16 (LN1 out) ----------------
__global__ __launch_bounds__(256) void ln1_transpose(
    const float* __restrict__ x, const float* __restrict__ w, const float* __restrict__ bb,
    unsigned short* __restrict__ xlh, float* __restrict__ t)
{
    __shared__ float tile[128][65];
    __shared__ float mu[64], rs[64];
    const int b = blockIdx.y;
    const int s0 = blockIdx.x * 64;
    const float* xb = x + (size_t)b * CNUM * S;
    for (int i = threadIdx.x; i < 128 * 64; i += 256) {
        int c = i >> 6, sl = i & 63;
        tile[c][sl] = xb[(size_t)c * S + s0 + sl];
    }
    __syncthreads();
    if (threadIdx.x < 64) {
        float sum = 0.f, sq = 0.f;
        for (int c = 0; c < 128; ++c) {
            float v = tile[c][threadIdx.x];
            sum += v; sq += v * v;
        }
        float m = sum * (1.f / 128.f);
        float var = sq * (1.f / 128.f) - m * m;
        mu[threadIdx.x] = m;
        rs[threadIdx.x] = rsqrtf(var + EPSLN);
    }
    __syncthreads();
    for (int i = threadIdx.x; i < 128 * 64; i += 256) {
        int c = i & 127, sl = i >> 7;
        float v = tile[c][sl];
        size_t idx = ((size_t)b * S + s0 + sl) * CNUM + c;
        t[idx] = v;
        xlh[idx] = f2b((v - mu[sl]) * rs[sl] * w[c] + bb[c]);
    }
}

// ---------------- weight convert+transpose fp32[K,N] -> bf16[N,K]; biases packed ----------------
__global__ __launch_bounds__(256) void convw(
    const float* __restrict__ wq, const float* __restrict__ wk, const float* __restrict__ wv,
    const float* __restrict__ wo, const float* __restrict__ w1, const float* __restrict__ w2,
    const float* __restrict__ bq, const float* __restrict__ bk, const float* __restrict__ bv,
    unsigned short* __restrict__ wqkvh, unsigned short* __restrict__ woh,
    unsigned short* __restrict__ w1h, unsigned short* __restrict__ w2h,
    float* __restrict__ bqkv)
{
    int a = blockIdx.y;
    int idx = blockIdx.x * 256 + threadIdx.x;
    if (a == 6) {
        if (idx < 128) bqkv[idx] = bq[idx];
        else if (idx < 256) bqkv[idx] = bk[idx - 128];
        else if (idx < 384) bqkv[idx] = bv[idx - 256];
        return;
    }
    const float* src; unsigned short* dst; int Nsh, Ksz;
    switch (a) {
        case 0: src = wq; dst = wqkvh;          Nsh = 7; Ksz = 128; break;
        case 1: src = wk; dst = wqkvh + 16384;  Nsh = 7; Ksz = 128; break;
        case 2: src = wv; dst = wqkvh + 32768;  Nsh = 7; Ksz = 128; break;
        case 3: src = wo; dst = woh;            Nsh = 7; Ksz = 128; break;
        case 4: src = w1; dst = w1h;            Nsh = 8; Ksz = 128; break;
        default: src = w2; dst = w2h;           Nsh = 7; Ksz = 256; break;
    }
    int total = Ksz << Nsh;
    if (idx >= total) return;
    int k = idx >> Nsh, n = idx & ((1 << Nsh) - 1);
    dst[n * Ksz + k] = f2b(src[idx]);
}

// ---------------- MFMA GEMM: C = A[M,KT](bf16) @ Bt[N,KT]^T(bf16) + bias, epilogues ----------------
// epi: 2 = fp32 +res -> C[M,N]
//      6 = gelu -> bf16 C[M,N]
//      7 = QKV combined (z=0,1: bf16 [M,128]; z=2: bf16 V written in pre-swizzled
//          per-64k-chunk LDS-image layout [b][kc][c*64 + ((g^(c&7))*8) + (k&7)])
//      8 = gelu + res -> fp32 out[b][col][s] (fused final transpose)
template<int KT>
__global__ __launch_bounds__(256) void gemm_mfma(
    const unsigned short* __restrict__ A, const unsigned short* __restrict__ Bt,
    const float* __restrict__ bias, const float* __restrict__ res,
    void* __restrict__ Cv, int N, int epi)
{
    constexpr int CH = KT / 8;
    constexpr int CSH = (KT == 128) ? 4 : 5;
    __shared__ unsigned short As[64 * KT];
    __shared__ unsigned short Bs[128 * KT];
    const int bm = blockIdx.y * 64;
    const int bn = blockIdx.x * 128;
    const int z = blockIdx.z;
    const unsigned short* Btz = (epi == 7) ? Bt + z * 16384 : Bt;
    const float* biasz = (epi == 7) ? bias + z * 128 : bias;
    const int tid = threadIdx.x;
    const int w = tid >> 6, l = tid & 63;
    const int rw = (w & 1) * 32, cw = (w >> 1) * 64;

    #pragma unroll
    for (int i = 0; i < (64 * CH) / 256; ++i) {
        int cid = i * 256 + tid;
        int r = cid >> CSH, c = cid & (CH - 1);
        int p = (c & ~15) | ((c ^ r) & 15);
        *(ulonglong2*)(As + r * KT + p * 8) =
            *(const ulonglong2*)(A + (size_t)(bm + r) * KT + c * 8);
    }
    #pragma unroll
    for (int i = 0; i < (128 * CH) / 256; ++i) {
        int cid = i * 256 + tid;
        int r = cid >> CSH, c = cid & (CH - 1);
        int p = (c & ~15) | ((c ^ r) & 15);
        *(ulonglong2*)(Bs + r * KT + p * 8) =
            *(const ulonglong2*)(Btz + (size_t)(bn + r) * KT + c * 8);
    }
    __syncthreads();

    f32x4 zero = {0.f, 0.f, 0.f, 0.f};
    f32x4 acc[2][4];
    #pragma unroll
    for (int i = 0; i < 2; ++i)
        #pragma unroll
        for (int j = 0; j < 4; ++j) acc[i][j] = zero;

    #pragma unroll
    for (int ks = 0; ks < KT / 32; ++ks) {
        int c_lin = ks * 4 + (l >> 4);
        bf16x8 a[2], bfr[4];
        #pragma unroll
        for (int i = 0; i < 2; ++i) {
            int m = rw + i * 16 + (l & 15);
            int p = (c_lin & ~15) | ((c_lin ^ m) & 15);
            a[i] = *(const bf16x8*)(As + m * KT + p * 8);
        }
        #pragma unroll
        for (int j = 0; j < 4; ++j) {
            int n = cw + j * 16 + (l & 15);
            int p = (c_lin & ~15) | ((c_lin ^ n) & 15);
            bfr[j] = *(const bf16x8*)(Bs + n * KT + p * 8);
        }
        #pragma unroll
        for (int i = 0; i < 2; ++i)
            #pragma unroll
            for (int j = 0; j < 4; ++j)
                acc[i][j] = __builtin_amdgcn_mfma_f32_16x16x32_bf16(a[i], bfr[j], acc[i][j], 0, 0, 0);
    }

    #pragma unroll
    for (int i = 0; i < 2; ++i) {
        int rowbase = bm + rw + i * 16 + (l >> 4) * 4;
        #pragma unroll
        for (int j = 0; j < 4; ++j) {
            int col = bn + cw + j * 16 + (l & 15);
            float v[4];
            #pragma unroll
            for (int reg = 0; reg < 4; ++reg) v[reg] = acc[i][j][reg] + biasz[col];
            if (epi == 2) {
                #pragma unroll
                for (int reg = 0; reg < 4; ++reg)
                    ((float*)Cv)[(size_t)(rowbase + reg) * N + col] =
                        v[reg] + res[(size_t)(rowbase + reg) * N + col];
            } else if (epi == 6) {
                #pragma unroll
                for (int reg = 0; reg < 4; ++reg)
                    ((unsigned short*)Cv)[(size_t)(rowbase + reg) * N + col] = f2b(gelu_exact(v[reg]));
            } else if (epi == 8) {
                int bb = rowbase >> 12, s = rowbase & 4095;
                float4 o;
                o.x = gelu_exact(v[0]) + res[(size_t)(rowbase + 0) * N + col];
                o.y = gelu_exact(v[1]) + res[(size_t)(rowbase + 1) * N + col];
                o.z = gelu_exact(v[2]) + res[(size_t)(rowbase + 2) * N + col];
                o.w = gelu_exact(v[3]) + res[(size_t)(rowbase + 3) * N + col];
                *(float4*)(((float*)Cv) + ((size_t)(bb * 128 + col)) * 4096 + s) = o;
            } else { // epi == 7
                if (z < 2) {
                    unsigned short* dst = ((unsigned short*)Cv) + (size_t)z * MTOT * 128;
                    #pragma unroll
                    for (int reg = 0; reg < 4; ++reg)
                        dst[(size_t)(rowbase + reg) * 128 + col] = f2b(v[reg]);
                } else {
                    // V pre-swizzled image: chunk = (bb*64 + s/64), 8192 elems each.
                    // offset = c*64 + ((g ^ (c&7))*8) + (s&7), g = (s>>3)&7.
                    int bb = rowbase >> 12, s = rowbase & 4095;
                    int kc = s >> 6, g = (s >> 3) & 7;
                    ushort4 o;
                    o.x = f2b(v[0]); o.y = f2b(v[1]); o.z = f2b(v[2]); o.w = f2b(v[3]);
                    *(ushort4*)(((unsigned short*)Cv) + (size_t)2 * MTOT * 128 +
                                (((size_t)bb * 64 + kc) << 13) +
                                col * 64 + ((g ^ (col & 7)) << 3) + (s & 7)) = o;
                }
            }
        }
    }
}

// ---------------- Pass A: column sums L[k] = sum_q f2b_ru(exp2(S[q,k])) — no P store ----------------
// grid (S/128 k-tiles, QSPLIT, BATCH). K-tile staged once; loop over q-tiles of this block's q-range.
__global__ __launch_bounds__(256) void colsum(
    const unsigned short* __restrict__ qh, const unsigned short* __restrict__ kh,
    float* __restrict__ psum_all)
{
    __shared__ unsigned short Qs[128 * 128];
    __shared__ unsigned short Ks[128 * 128];
    __shared__ float csum[2][128];
    const int b = blockIdx.z;
    const unsigned short* Q = qh + (size_t)b * S * 128;
    const unsigned short* Km = kh + (size_t)b * S * 128;
    const int bn = blockIdx.x * 128;
    const int q0 = blockIdx.y * (S / QSPLIT);
    const int tid = threadIdx.x;
    const int w = tid >> 6, l = tid & 63;
    const int wr = (w >> 1) * 64, wc = (w & 1) * 64;
    const int lm = l & 15, lq = l >> 4;

    // stage K tile once (swizzled, scores_p pattern)
    #pragma unroll
    for (int i = 0; i < 8; ++i) {
        int cid = i * 256 + tid;
        int r = cid >> 4, c = cid & 15;
        int p = c ^ (r & 15);
        *(ulonglong2*)(Ks + r * 128 + p * 8) =
            *(const ulonglong2*)(Km + (size_t)(bn + r) * 128 + c * 8);
    }

    float jsum[4] = {0.f, 0.f, 0.f, 0.f};
    for (int qt = 0; qt < (S / QSPLIT) / 128; ++qt) {
        __syncthreads();   // protect Qs from previous iteration's readers (also covers Ks stage on qt=0)
        #pragma unroll
        for (int i = 0; i < 8; ++i) {
            int cid = i * 256 + tid;
            int r = cid >> 4, c = cid & 15;
            int p = c ^ (r & 15);
            *(ulonglong2*)(Qs + r * 128 + p * 8) =
                *(const ulonglong2*)(Q + (size_t)(q0 + qt * 128 + r) * 128 + c * 8);
        }
        __syncthreads();

        f32x4 zero = {0.f, 0.f, 0.f, 0.f};
        f32x4 acc[4][4];
        #pragma unroll
        for (int i = 0; i < 4; ++i)
            #pragma unroll
            for (int j = 0; j < 4; ++j) acc[i][j] = zero;

        #pragma unroll
        for (int ks = 0; ks < 4; ++ks) {
            bf16x8 a[4], bfr[4];
            #pragma unroll
            for (int i = 0; i < 4; ++i) {
                int m = wr + i * 16 + lm;
                int p = (ks * 4 + lq) ^ (m & 15);
                a[i] = *(const bf16x8*)(Qs + m * 128 + p * 8);
            }
            #pragma unroll
            for (int j = 0; j < 4; ++j) {
                int n = wc + j * 16 + lm;
                int p = (ks * 4 + lq) ^ (n & 15);
                bfr[j] = *(const bf16x8*)(Ks + n * 128 + p * 8);
            }
            #pragma unroll
            for (int i = 0; i < 4; ++i)
                #pragma unroll
                for (int j = 0; j < 4; ++j)
                    acc[i][j] = __builtin_amdgcn_mfma_f32_16x16x32_bf16(a[i], bfr[j], acc[i][j], 0, 0, 0);
        }

        #pragma unroll
        for (int i = 0; i < 4; ++i)
            #pragma unroll
            for (int j = 0; j < 4; ++j)
                #pragma unroll
                for (int reg = 0; reg < 4; ++reg)
                    jsum[j] += b2f(f2b_ru(exp2f(acc[i][j][reg] * SCLOG2E)));
    }

    #pragma unroll
    for (int j = 0; j < 4; ++j) {
        jsum[j] += __shfl_xor(jsum[j], 16);
        jsum[j] += __shfl_xor(jsum[j], 32);
    }
    if (l < 16) {
        #pragma unroll
        for (int j = 0; j < 4; ++j)
            csum[w >> 1][wc + j * 16 + l] = jsum[j];
    }
    __syncthreads();
    if (tid < 128)
        psum_all[((size_t)(blockIdx.y * BATCH + b)) * S + bn + tid] = csum[0][tid] + csum[1][tid];
}

// ---------------- fold 1/L into V image (in place, bf16); k recovered from swizzled offset ----------------
__global__ __launch_bounds__(256) void vscale(
    unsigned short* __restrict__ Vimg_all, const float* __restrict__ psum_all)
{
    const int b = blockIdx.z;
    unsigned short* Vimg = Vimg_all + (size_t)b * CNUM * S;
    int i = (blockIdx.x * 256 + threadIdx.x) * 4;   // elem offset within batch image
    int kc = i >> 13;
    int off = i & 8191;
    int c = off >> 6;
    int p = (off >> 3) & 7;
    int g = p ^ (c & 7);
    int k = kc * 64 + g * 8 + (off & 7);
    float4 L = *(const float4*)(psum_all + (size_t)b * S + k);
    #pragma unroll
    for (int t = 1; t < QSPLIT; ++t) {
        float4 Lt = *(const float4*)(psum_all + ((size_t)(t * BATCH + b)) * S + k);
        L.x += Lt.x; L.y += Lt.y; L.z += Lt.z; L.w += Lt.w;
    }
    ushort4 v = *(ushort4*)(Vimg + i);
    v.x = f2b(b2f(v.x) / L.x);
    v.y = f2b(b2f(v.y) / L.y);
    v.z = f2b(b2f(v.z) / L.z);
    v.w = f2b(b2f(v.w) / L.w);
    *(ushort4*)(Vimg + i) = v;
}

// ---------------- fused attention: out_part = exp2(Q K^T) @ Vhat, k-split ----------------
// grid (KSPLIT, S/128, BATCH), 256 thr, 4 blocks/CU. Q held in registers; QK^T is computed
// TRANSPOSED (mfma(K,Q) -> S^T) so each lane holds 4 consecutive k per reg quad: P pairs pack
// with v_cvt_pk_bf16_f32 into 8 ds_write_b32 (padded [128][18 u32] buffer, ~2-way banks),
// read back as uint2 pairs for the PV A-fragment. 32-k K tiles (8 KB); V 64-chunk staged
// every other iteration via global_load_lds from the pre-swizzled image.
__global__ __launch_bounds__(256, 4) void fused_attnv(
    const unsigned short* __restrict__ qh, const unsigned short* __restrict__ kh,
    const unsigned short* __restrict__ Vimg_all, unsigned short* __restrict__ parts)
{
    __shared__ unsigned short Ks[32 * 128];      // 8 KB, swizzled p = c ^ (r&15)
    __shared__ unsigned short Vls[128 * 64];     // 16 KB, image chunk (linear DMA)
    __shared__ unsigned int   Ps[128 * 18];      // 9 KB, P half-tile [128 q][16+2 u32]
    const int b = blockIdx.z;
    const unsigned short* Qm = qh + (size_t)b * S * 128;
    const unsigned short* Km = kh + (size_t)b * S * 128;
    const unsigned short* Vimg = Vimg_all + (((size_t)b * 64) << 13);
    unsigned short* Pout = parts + (size_t)blockIdx.x * ((size_t)MTOT * CNUM)
                                 + (size_t)b * S * CNUM;
    const int q0 = blockIdx.y * 128;
    const int kb0 = blockIdx.x * (S / KSPLIT);          // 512-k range
    const int kc0 = blockIdx.x * (S / KSPLIT / 64);     // first 64-k V chunk (x*8)
    const int tid = threadIdx.x;
    const int w = tid >> 6, l = tid & 63;
    const int lm = l & 15, lq = l >> 4;
    const int row0 = q0 + w * 32;
    const int prow0 = w * 32;                            // block-local q row base

    // Q fragments (B-operand layout), persistent across all k-tiles
    bf16x8 aq[2][4];
    #pragma unroll
    for (int i = 0; i < 2; ++i)
        #pragma unroll
        for (int ks = 0; ks < 4; ++ks)
            aq[i][ks] = *(const bf16x8*)(Qm + (size_t)(row0 + i * 16 + lm) * 128 + (ks * 4 + lq) * 8);

    f32x4 zero = {0.f, 0.f, 0.f, 0.f};
    f32x4 acco[2][8];
    #pragma unroll
    for (int i = 0; i < 2; ++i)
        #pragma unroll
        for (int j = 0; j < 8; ++j) acco[i][j] = zero;

    for (int kt = 0; kt < S / KSPLIT / 32; ++kt) {       // 16 iterations of 32 k
        const int kb = kb0 + kt * 32;
        __syncthreads();                                  // previous readers of Ks/Vls done
        // stage K tile [32][128] with read swizzle (reg staging)
        #pragma unroll
        for (int i2 = 0; i2 < 2; ++i2) {
            int cid = i2 * 256 + tid;
            int r = cid >> 4, c = cid & 15;
            int p = c ^ (r & 15);
            *(ulonglong2*)(Ks + r * 128 + p * 8) =
                *(const ulonglong2*)(Km + (size_t)(kb + r) * 128 + c * 8);
        }
        // stage Vhat 64-chunk every other iteration (pre-swizzled image, linear DMA)
        if ((kt & 1) == 0) {
            const unsigned short* src = Vimg + ((size_t)(kc0 + (kt >> 1)) << 13) + tid * 8;
            #pragma unroll
            for (int i2 = 0; i2 < 4; ++i2)
                gl_lds16(src + i2 * 2048, &Vls[(i2 * 256 + tid) * 8]);
        }
        __syncthreads();

        // transposed QK^T: accT[ki][qj], lane holds S[q=qj*16+lm][k=ki*16+lq*4+reg]
        f32x4 accT[2][2];
        #pragma unroll
        for (int ki = 0; ki < 2; ++ki)
            #pragma unroll
            for (int qj = 0; qj < 2; ++qj) accT[ki][qj] = zero;
        #pragma unroll
        for (int ks = 0; ks < 4; ++ks) {
            bf16x8 kfr[2];
            #pragma unroll
            for (int ki = 0; ki < 2; ++ki) {
                int n = ki * 16 + lm;
                int p = (ks * 4 + lq) ^ (n & 15);
                kfr[ki] = *(const bf16x8*)(Ks + n * 128 + p * 8);
            }
            #pragma unroll
            for (int ki = 0; ki < 2; ++ki)
                #pragma unroll
                for (int qj = 0; qj < 2; ++qj)
                    accT[ki][qj] = __builtin_amdgcn_mfma_f32_16x16x32_bf16(kfr[ki], aq[qj][ks], accT[ki][qj], 0, 0, 0);
        }

        // P = exp2 -> packed pairs -> Ps[q][ki*8 + lq*2 + r2] (one base VGPR + imm offsets)
        #pragma unroll
        for (int qj = 0; qj < 2; ++qj) {
            unsigned int* pw = Ps + (prow0 + qj * 16 + lm) * 18 + lq * 2;
            #pragma unroll
            for (int ki = 0; ki < 2; ++ki)
                #pragma unroll
                for (int r2 = 0; r2 < 2; ++r2) {
                    float e0 = exp2f(accT[ki][qj][2 * r2]     * SCLOG2E);
                    float e1 = exp2f(accT[ki][qj][2 * r2 + 1] * SCLOG2E);
                    unsigned int pk;
                    asm("v_cvt_pk_bf16_f32 %0, %1, %2" : "=v"(pk) : "v"(e0), "v"(e1));
                    pw[ki * 8 + r2] = pk;
                }
        }

        // PV A-fragments from Ps (8 consecutive k = 4 consecutive u32 at lq*4)
        bf16x8 ap[2];
        #pragma unroll
        for (int i = 0; i < 2; ++i) {
            const unsigned int* pr = Ps + (prow0 + i * 16 + lm) * 18 + lq * 4;
            uint2 u0 = *(const uint2*)(pr);
            uint2 u1 = *(const uint2*)(pr + 2);
            u32x4 uu = {u0.x, u0.y, u1.x, u1.y};
            ap[i] = __builtin_bit_cast(bf16x8, uu);
        }
        // PV: acco += P @ Vhat  (V half selected by kt parity)
        const int vh = (kt & 1) * 4;
        #pragma unroll
        for (int j = 0; j < 8; ++j) {
            int n = j * 16 + lm;
            bf16x8 bv = *(const bf16x8*)(Vls + n * 64 + (((vh + lq) ^ (n & 7)) << 3));
            acco[0][j] = __builtin_amdgcn_mfma_f32_16x16x32_bf16(ap[0], bv, acco[0][j], 0, 0, 0);
            acco[1][j] = __builtin_amdgcn_mfma_f32_16x16x32_bf16(ap[1], bv, acco[1][j], 0, 0, 0);
        }
    }

    #pragma unroll
    for (int i = 0; i < 2; ++i) {
        int rowb = row0 + i * 16 + lq * 4;
        #pragma unroll
        for (int j = 0; j < 8; ++j) {
            int col = j * 16 + lm;
            #pragma unroll
            for (int reg = 0; reg < 4; ++reg)
                Pout[(size_t)(rowb + reg) * CNUM + col] = f2b(acco[i][j][reg]);
        }
    }
}

// ---------------- reduce KSPLIT bf16 partials -> bf16 attouth ----------------
__global__ __launch_bounds__(256) void reduce8b(
    const ushort4* __restrict__ parts, ushort4* __restrict__ dst)
{
    size_t i = (size_t)blockIdx.x * 256 + threadIdx.x;
    const size_t stride = (size_t)MTOT * CNUM / 4;
    float sx = 0.f, sy = 0.f, sz = 0.f, sw = 0.f;
    #pragma unroll
    for (int p = 0; p < KSPLIT; ++p) {
        ushort4 v = parts[i + p * stride];
        sx += b2f(v.x); sy += b2f(v.y); sz += b2f(v.z); sw += b2f(v.w);
    }
    ushort4 o;
    o.x = f2b(sx); o.y = f2b(sy); o.z = f2b(sz); o.w = f2b(sw);
    dst[i] = o;
}

// ---------------- LayerNorm rows -> bf16 ----------------
__global__ __launch_bounds__(256) void ln_rows(
    const float* __restrict__ y, const float* __restrict__ w, const float* __restrict__ bb,
    unsigned short* __restrict__ zh)
{
    int row = blockIdx.x * 4 + (threadIdx.x >> 6);
    int lane = threadIdx.x & 63;
    const float* yr = y + (size_t)row * CNUM;
    float v0 = yr[lane], v1 = yr[lane + 64];
    float sum = v0 + v1, sq = v0 * v0 + v1 * v1;
    #pragma unroll
    for (int off = 32; off; off >>= 1) {
        sum += __shfl_xor(sum, off);
        sq  += __shfl_xor(sq, off);
    }
    float mean = sum * (1.f / 128.f);
    float var = sq * (1.f / 128.f) - mean * mean;
    float r = rsqrtf(var + EPSLN);
    zh[(size_t)row * CNUM + lane]      = f2b((v0 - mean) * r * w[lane] + bb[lane]);
    zh[(size_t)row * CNUM + lane + 64] = f2b((v1 - mean) * r * w[lane + 64] + bb[lane + 64]);
}

extern "C" void kernel_launch(void* const* d_in, const int* in_sizes, int n_in,
                              void* d_out, int out_size, void* d_ws, size_t ws_size,
                              hipStream_t stream)
{
    (void)in_sizes; (void)n_in; (void)out_size; (void)ws_size;
    const float* x    = (const float*)d_in[0];
    const float* ln1w = (const float*)d_in[1];
    const float* ln1b = (const float*)d_in[2];
    const float* wq   = (const float*)d_in[3];
    const float* bq   = (const float*)d_in[4];
    const float* wk   = (const float*)d_in[5];
    const float* bk   = (const float*)d_in[6];
    const float* wv   = (const float*)d_in[7];
    const float* bv   = (const float*)d_in[8];
    const float* wo   = (const float*)d_in[9];
    const float* bo   = (const float*)d_in[10];
    const float* ln2w = (const float*)d_in[11];
    const float* ln2b = (const float*)d_in[12];
    const float* w1   = (const float*)d_in[13];
    const float* b1   = (const float*)d_in[14];
    const float* w2   = (const float*)d_in[15];
    const float* b2   = (const float*)d_in[16];
    float* out = (float*)d_out;

    float* ws = (float*)d_ws;
    const size_t NSC = (size_t)MTOT * CNUM;            // 2,097,152
    float* t      = ws;
    float* y      = t + NSC;
    float* psum   = y + NSC;                           // [QSPLIT][B][S]
    unsigned short* parts = (unsigned short*)(psum + (size_t)QSPLIT * BATCH * S); // [KSPLIT][B][S][C]
    unsigned short* xlh = parts + (size_t)KSPLIT * NSC;
    unsigned short* qh  = xlh + NSC;
    unsigned short* kh  = qh + NSC;                    // Vt must follow kh (epi 7 contiguity)
    unsigned short* Vt  = kh + NSC;                    // pre-swizzled V image
    unsigned short* attouth = Vt + NSC;
    unsigned short* zh  = attouth + NSC;
    unsigned short* hh  = zh + NSC;                    // [M,256] bf16
    unsigned short* wqkvh = hh + (size_t)MTOT * 256;
    unsigned short* woh = wqkvh + 3 * 16384;
    unsigned short* w1h = woh + 16384;                 // [256][128]
    unsigned short* w2h = w1h + 32768;                 // [128][256]
    float* bqkv = (float*)(w2h + 32768);               // [384]

    ln1_transpose<<<dim3(S / 64, BATCH), 256, 0, stream>>>(x, ln1w, ln1b, xlh, t);
    convw<<<dim3(128, 7), 256, 0, stream>>>(wq, wk, wv, wo, w1, w2, bq, bk, bv,
                                            wqkvh, woh, w1h, w2h, bqkv);

    // QKV: one launch, z = {q, k, v(image)}
    gemm_mfma<128><<<dim3(1, MTOT / 64, 3), 256, 0, stream>>>(
        xlh, wqkvh, bqkv, nullptr, qh, 128, 7);

    colsum<<<dim3(S / 128, QSPLIT, BATCH), 256, 0, stream>>>(qh, kh, psum);
    vscale<<<dim3(CNUM * S / 4 / 256, 1, BATCH), 256, 0, stream>>>(Vt, psum);
    fused_attnv<<<dim3(KSPLIT, S / 128, BATCH), 256, 0, stream>>>(qh, kh, Vt, parts);
    reduce8b<<<NSC / 4 / 256, 256, 0, stream>>>((const ushort4*)parts, (ushort4*)attouth);

    // y = attouth @ wo + bo + t
    gemm_mfma<128><<<dim3(1, MTOT / 64), 256, 0, stream>>>(attouth, woh, bo, t, y, 128, 2);
    ln_rows<<<MTOT / 4, 256, 0, stream>>>(y, ln2w, ln2b, zh);
    // hh = gelu(zh @ w1 + b1) -> bf16
    gemm_mfma<128><<<dim3(2, MTOT / 64), 256, 0, stream>>>(zh, w1h, b1, nullptr, hh, 256, 6);
    // out[b][c][s] = gelu(hh @ w2 + b2) + y   (fused transpose)
    gemm_mfma<256><<<dim3(1, MTOT / 64), 256, 0, stream>>>(hh, w2h, b2, y, out, 128, 8);
}

// Round 5
// 246.847 us; speedup vs baseline: 1.0743x; 1.0743x over previous
//
#include <hip/hip_runtime.h>
#include <math.h>

#define S 4096
#define CNUM 128
#define BATCH 4
#define MTOT (BATCH * S)
#define SCLOG2E 0.36067376022224085f   // 0.25 * log2(e): scores in log2 domain
#define EPSLN 1e-5f
#define KSPLIT 8                        // k-range split for fused attn partials
#define QSPLIT 8                        // q-range split for column-sum pass

typedef __attribute__((ext_vector_type(8))) short bf16x8;
typedef __attribute__((ext_vector_type(4))) float f32x4;
typedef __attribute__((ext_vector_type(4))) unsigned int u32x4;

__device__ __forceinline__ float gelu_exact(float x) {
    return 0.5f * x * (1.0f + erff(x * 0.7071067811865476f));
}

__device__ __forceinline__ unsigned short f2b(float f) {
    union { float f; unsigned int u; } v; v.f = f;
    unsigned int r = (v.u + 0x7FFFu + ((v.u >> 16) & 1u)) >> 16;
    return (unsigned short)r;
}
// cheap round-half-up for positive values (2 ops)
__device__ __forceinline__ unsigned short f2b_ru(float f) {
    return (unsigned short)((__float_as_uint(f) + 0x8000u) >> 16);
}
__device__ __forceinline__ float b2f(unsigned short u) {
    return __uint_as_float((unsigned)u << 16);
}

// async 16B global->LDS (direct DMA, no VGPR round trip)
__device__ __forceinline__ void gl_lds16(const void* g, void* l) {
    __builtin_amdgcn_global_load_lds(
        (__attribute__((address_space(1))) void*)g,
        (__attribute__((address_space(3))) void*)l, 16, 0, 0);
}

// ---------------- transpose [B,C,S] -> [B,S,C]: t fp32 (residual), xlh bf16 (LN1 out) ----------------
__global__ __launch_bounds__(256) void ln1_transpose(
    const float* __restrict__ x, const float* __restrict__ w, const float* __restrict__ bb,
    unsigned short* __restrict__ xlh, float* __restrict__ t)
{
    __shared__ float tile[128][65];
    __shared__ float mu[64], rs[64];
    const int b = blockIdx.y;
    const int s0 = blockIdx.x * 64;
    const float* xb = x + (size_t)b * CNUM * S;
    for (int i = threadIdx.x; i < 128 * 64; i += 256) {
        int c = i >> 6, sl = i & 63;
        tile[c][sl] = xb[(size_t)c * S + s0 + sl];
    }
    __syncthreads();
    if (threadIdx.x < 64) {
        float sum = 0.f, sq = 0.f;
        for (int c = 0; c < 128; ++c) {
            float v = tile[c][threadIdx.x];
            sum += v; sq += v * v;
        }
        float m = sum * (1.f / 128.f);
        float var = sq * (1.f / 128.f) - m * m;
        mu[threadIdx.x] = m;
        rs[threadIdx.x] = rsqrtf(var + EPSLN);
    }
    __syncthreads();
    for (int i = threadIdx.x; i < 128 * 64; i += 256) {
        int c = i & 127, sl = i >> 7;
        float v = tile[c][sl];
        size_t idx = ((size_t)b * S + s0 + sl) * CNUM + c;
        t[idx] = v;
        xlh[idx] = f2b((v - mu[sl]) * rs[sl] * w[c] + bb[c]);
    }
}

// ---------------- weight convert+transpose fp32[K,N] -> bf16[N,K]; biases packed ----------------
__global__ __launch_bounds__(256) void convw(
    const float* __restrict__ wq, const float* __restrict__ wk, const float* __restrict__ wv,
    const float* __restrict__ wo, const float* __restrict__ w1, const float* __restrict__ w2,
    const float* __restrict__ bq, const float* __restrict__ bk, const float* __restrict__ bv,
    unsigned short* __restrict__ wqkvh, unsigned short* __restrict__ woh,
    unsigned short* __restrict__ w1h, unsigned short* __restrict__ w2h,
    float* __restrict__ bqkv)
{
    int a = blockIdx.y;
    int idx = blockIdx.x * 256 + threadIdx.x;
    if (a == 6) {
        if (idx < 128) bqkv[idx] = bq[idx];
        else if (idx < 256) bqkv[idx] = bk[idx - 128];
        else if (idx < 384) bqkv[idx] = bv[idx - 256];
        return;
    }
    const float* src; unsigned short* dst; int Nsh, Ksz;
    switch (a) {
        case 0: src = wq; dst = wqkvh;          Nsh = 7; Ksz = 128; break;
        case 1: src = wk; dst = wqkvh + 16384;  Nsh = 7; Ksz = 128; break;
        case 2: src = wv; dst = wqkvh + 32768;  Nsh = 7; Ksz = 128; break;
        case 3: src = wo; dst = woh;            Nsh = 7; Ksz = 128; break;
        case 4: src = w1; dst = w1h;            Nsh = 8; Ksz = 128; break;
        default: src = w2; dst = w2h;           Nsh = 7; Ksz = 256; break;
    }
    int total = Ksz << Nsh;
    if (idx >= total) return;
    int k = idx >> Nsh, n = idx & ((1 << Nsh) - 1);
    dst[n * Ksz + k] = f2b(src[idx]);
}

// ---------------- MFMA GEMM: C = A[M,KT](bf16) @ Bt[N,KT]^T(bf16) + bias, epilogues ----------------
// EPI: 3 = fp32 +res -> y[M,N] AND fused LN2 -> bf16 zh[M,N]
//      6 = gelu -> bf16 C[M,N]
//      7 = QKV combined (z=0,1: bf16 [M,128]; z=2: bf16 V written in pre-swizzled
//          per-64k-chunk LDS-image layout)
//      8 = gelu + res -> fp32 out[b][col][s] (fused final transpose)
template<int KT, int EPI>
__global__ __launch_bounds__(256) void gemm_mfma(
    const unsigned short* __restrict__ A, const unsigned short* __restrict__ Bt,
    const float* __restrict__ bias, const float* __restrict__ res,
    void* __restrict__ Cv, void* __restrict__ Cv2,
    const float* __restrict__ wln, const float* __restrict__ bln, int N)
{
    constexpr int CH = KT / 8;
    constexpr int CSH = (KT == 128) ? 4 : 5;
    __shared__ unsigned short As[64 * KT];
    __shared__ unsigned short Bs[128 * KT];
    __shared__ float2 lnred[2][64];              // EPI==3 only (1 KB)
    const int bm = blockIdx.y * 64;
    const int bn = blockIdx.x * 128;
    const int z = blockIdx.z;
    const unsigned short* Btz = (EPI == 7) ? Bt + z * 16384 : Bt;
    const float* biasz = (EPI == 7) ? bias + z * 128 : bias;
    const int tid = threadIdx.x;
    const int w = tid >> 6, l = tid & 63;
    const int rw = (w & 1) * 32, cw = (w >> 1) * 64;
    const int lm = l & 15, lq = l >> 4;

    #pragma unroll
    for (int i = 0; i < (64 * CH) / 256; ++i) {
        int cid = i * 256 + tid;
        int r = cid >> CSH, c = cid & (CH - 1);
        int p = (c & ~15) | ((c ^ r) & 15);
        *(ulonglong2*)(As + r * KT + p * 8) =
            *(const ulonglong2*)(A + (size_t)(bm + r) * KT + c * 8);
    }
    #pragma unroll
    for (int i = 0; i < (128 * CH) / 256; ++i) {
        int cid = i * 256 + tid;
        int r = cid >> CSH, c = cid & (CH - 1);
        int p = (c & ~15) | ((c ^ r) & 15);
        *(ulonglong2*)(Bs + r * KT + p * 8) =
            *(const ulonglong2*)(Btz + (size_t)(bn + r) * KT + c * 8);
    }
    __syncthreads();

    f32x4 zero = {0.f, 0.f, 0.f, 0.f};
    f32x4 acc[2][4];
    #pragma unroll
    for (int i = 0; i < 2; ++i)
        #pragma unroll
        for (int j = 0; j < 4; ++j) acc[i][j] = zero;

    #pragma unroll
    for (int ks = 0; ks < KT / 32; ++ks) {
        int c_lin = ks * 4 + lq;
        bf16x8 a[2], bfr[4];
        #pragma unroll
        for (int i = 0; i < 2; ++i) {
            int m = rw + i * 16 + lm;
            int p = (c_lin & ~15) | ((c_lin ^ m) & 15);
            a[i] = *(const bf16x8*)(As + m * KT + p * 8);
        }
        #pragma unroll
        for (int j = 0; j < 4; ++j) {
            int n = cw + j * 16 + lm;
            int p = (c_lin & ~15) | ((c_lin ^ n) & 15);
            bfr[j] = *(const bf16x8*)(Bs + n * KT + p * 8);
        }
        #pragma unroll
        for (int i = 0; i < 2; ++i)
            #pragma unroll
            for (int j = 0; j < 4; ++j)
                acc[i][j] = __builtin_amdgcn_mfma_f32_16x16x32_bf16(a[i], bfr[j], acc[i][j], 0, 0, 0);
    }

    if (EPI == 3) {
        // y = acc + bias + res; then fused LN over the 128-col rows of this 64-row block.
        float vv[2][4][4];
        #pragma unroll
        for (int i = 0; i < 2; ++i) {
            int rowbase = bm + rw + i * 16 + lq * 4;
            #pragma unroll
            for (int j = 0; j < 4; ++j) {
                int col = bn + cw + j * 16 + lm;
                #pragma unroll
                for (int reg = 0; reg < 4; ++reg)
                    vv[i][j][reg] = acc[i][j][reg] + biasz[col] +
                                    res[(size_t)(rowbase + reg) * N + col];
            }
        }
        // per-row partials over this wave's 64-col half: in-thread j-sum, then 16-lane shfl
        #pragma unroll
        for (int i = 0; i < 2; ++i)
            #pragma unroll
            for (int reg = 0; reg < 4; ++reg) {
                float s = 0.f, q = 0.f;
                #pragma unroll
                for (int j = 0; j < 4; ++j) {
                    float xv = vv[i][j][reg];
                    s += xv; q += xv * xv;
                }
                #pragma unroll
                for (int off = 1; off < 16; off <<= 1) {
                    s += __shfl_xor(s, off);
                    q += __shfl_xor(q, off);
                }
                if (lm == 0) {
                    float2 sq2; sq2.x = s; sq2.y = q;
                    lnred[cw >> 6][rw + i * 16 + lq * 4 + reg] = sq2;
                }
            }
        __syncthreads();
        #pragma unroll
        for (int i = 0; i < 2; ++i) {
            #pragma unroll
            for (int reg = 0; reg < 4; ++reg) {
                int lrow = rw + i * 16 + lq * 4 + reg;
                int row = bm + lrow;
                float2 h0 = lnred[0][lrow], h1 = lnred[1][lrow];
                float mean = (h0.x + h1.x) * (1.f / 128.f);
                float var  = (h0.y + h1.y) * (1.f / 128.f) - mean * mean;
                float rs = rsqrtf(var + EPSLN);
                #pragma unroll
                for (int j = 0; j < 4; ++j) {
                    int col = bn + cw + j * 16 + lm;
                    float xv = vv[i][j][reg];
                    ((float*)Cv)[(size_t)row * N + col] = xv;
                    ((unsigned short*)Cv2)[(size_t)row * N + col] =
                        f2b((xv - mean) * rs * wln[col] + bln[col]);
                }
            }
        }
        return;
    }

    #pragma unroll
    for (int i = 0; i < 2; ++i) {
        int rowbase = bm + rw + i * 16 + lq * 4;
        #pragma unroll
        for (int j = 0; j < 4; ++j) {
            int col = bn + cw + j * 16 + lm;
            float v[4];
            #pragma unroll
            for (int reg = 0; reg < 4; ++reg) v[reg] = acc[i][j][reg] + biasz[col];
            if (EPI == 6) {
                #pragma unroll
                for (int reg = 0; reg < 4; ++reg)
                    ((unsigned short*)Cv)[(size_t)(rowbase + reg) * N + col] = f2b(gelu_exact(v[reg]));
            } else if (EPI == 8) {
                int bb = rowbase >> 12, s = rowbase & 4095;
                float4 o;
                o.x = gelu_exact(v[0]) + res[(size_t)(rowbase + 0) * N + col];
                o.y = gelu_exact(v[1]) + res[(size_t)(rowbase + 1) * N + col];
                o.z = gelu_exact(v[2]) + res[(size_t)(rowbase + 2) * N + col];
                o.w = gelu_exact(v[3]) + res[(size_t)(rowbase + 3) * N + col];
                *(float4*)(((float*)Cv) + ((size_t)(bb * 128 + col)) * 4096 + s) = o;
            } else if (EPI == 7) {
                if (z < 2) {
                    unsigned short* dst = ((unsigned short*)Cv) + (size_t)z * MTOT * 128;
                    #pragma unroll
                    for (int reg = 0; reg < 4; ++reg)
                        dst[(size_t)(rowbase + reg) * 128 + col] = f2b(v[reg]);
                } else {
                    // V pre-swizzled image: chunk = (bb*64 + s/64), 8192 elems each.
                    // offset = c*64 + ((g ^ (c&7))*8) + (s&7), g = (s>>3)&7.
                    int bb = rowbase >> 12, s = rowbase & 4095;
                    int kc = s >> 6, g = (s >> 3) & 7;
                    ushort4 o;
                    o.x = f2b(v[0]); o.y = f2b(v[1]); o.z = f2b(v[2]); o.w = f2b(v[3]);
                    *(ushort4*)(((unsigned short*)Cv) + (size_t)2 * MTOT * 128 +
                                (((size_t)bb * 64 + kc) << 13) +
                                col * 64 + ((g ^ (col & 7)) << 3) + (s & 7)) = o;
                }
            }
        }
    }
}

// ---------------- Pass A: column sums L[k] = sum_q f2b_ru(exp2(S[q,k])) — no P store ----------------
// grid (S/128 k-tiles, QSPLIT, BATCH). K-tile staged once; loop over q-tiles of this block's q-range.
__global__ __launch_bounds__(256) void colsum(
    const unsigned short* __restrict__ qh, const unsigned short* __restrict__ kh,
    float* __restrict__ psum_all)
{
    __shared__ unsigned short Qs[128 * 128];
    __shared__ unsigned short Ks[128 * 128];
    __shared__ float csum[2][128];
    const int b = blockIdx.z;
    const unsigned short* Q = qh + (size_t)b * S * 128;
    const unsigned short* Km = kh + (size_t)b * S * 128;
    const int bn = blockIdx.x * 128;
    const int q0 = blockIdx.y * (S / QSPLIT);
    const int tid = threadIdx.x;
    const int w = tid >> 6, l = tid & 63;
    const int wr = (w >> 1) * 64, wc = (w & 1) * 64;
    const int lm = l & 15, lq = l >> 4;

    // stage K tile once (swizzled, scores_p pattern)
    #pragma unroll
    for (int i = 0; i < 8; ++i) {
        int cid = i * 256 + tid;
        int r = cid >> 4, c = cid & 15;
        int p = c ^ (r & 15);
        *(ulonglong2*)(Ks + r * 128 + p * 8) =
            *(const ulonglong2*)(Km + (size_t)(bn + r) * 128 + c * 8);
    }

    float jsum[4] = {0.f, 0.f, 0.f, 0.f};
    for (int qt = 0; qt < (S / QSPLIT) / 128; ++qt) {
        __syncthreads();   // protect Qs from previous iteration's readers (also covers Ks stage on qt=0)
        #pragma unroll
        for (int i = 0; i < 8; ++i) {
            int cid = i * 256 + tid;
            int r = cid >> 4, c = cid & 15;
            int p = c ^ (r & 15);
            *(ulonglong2*)(Qs + r * 128 + p * 8) =
                *(const ulonglong2*)(Q + (size_t)(q0 + qt * 128 + r) * 128 + c * 8);
        }
        __syncthreads();

        f32x4 zero = {0.f, 0.f, 0.f, 0.f};
        f32x4 acc[4][4];
        #pragma unroll
        for (int i = 0; i < 4; ++i)
            #pragma unroll
            for (int j = 0; j < 4; ++j) acc[i][j] = zero;

        #pragma unroll
        for (int ks = 0; ks < 4; ++ks) {
            bf16x8 a[4], bfr[4];
            #pragma unroll
            for (int i = 0; i < 4; ++i) {
                int m = wr + i * 16 + lm;
                int p = (ks * 4 + lq) ^ (m & 15);
                a[i] = *(const bf16x8*)(Qs + m * 128 + p * 8);
            }
            #pragma unroll
            for (int j = 0; j < 4; ++j) {
                int n = wc + j * 16 + lm;
                int p = (ks * 4 + lq) ^ (n & 15);
                bfr[j] = *(const bf16x8*)(Ks + n * 128 + p * 8);
            }
            #pragma unroll
            for (int i = 0; i < 4; ++i)
                #pragma unroll
                for (int j = 0; j < 4; ++j)
                    acc[i][j] = __builtin_amdgcn_mfma_f32_16x16x32_bf16(a[i], bfr[j], acc[i][j], 0, 0, 0);
        }

        #pragma unroll
        for (int i = 0; i < 4; ++i)
            #pragma unroll
            for (int j = 0; j < 4; ++j)
                #pragma unroll
                for (int reg = 0; reg < 4; ++reg)
                    jsum[j] += b2f(f2b_ru(exp2f(acc[i][j][reg] * SCLOG2E)));
    }

    #pragma unroll
    for (int j = 0; j < 4; ++j) {
        jsum[j] += __shfl_xor(jsum[j], 16);
        jsum[j] += __shfl_xor(jsum[j], 32);
    }
    if (l < 16) {
        #pragma unroll
        for (int j = 0; j < 4; ++j)
            csum[w >> 1][wc + j * 16 + l] = jsum[j];
    }
    __syncthreads();
    if (tid < 128)
        psum_all[((size_t)(blockIdx.y * BATCH + b)) * S + bn + tid] = csum[0][tid] + csum[1][tid];
}

// ---------------- fold 1/L into V image (in place, bf16); k recovered from swizzled offset ----------------
__global__ __launch_bounds__(256) void vscale(
    unsigned short* __restrict__ Vimg_all, const float* __restrict__ psum_all)
{
    const int b = blockIdx.z;
    unsigned short* Vimg = Vimg_all + (size_t)b * CNUM * S;
    int i = (blockIdx.x * 256 + threadIdx.x) * 4;   // elem offset within batch image
    int kc = i >> 13;
    int off = i & 8191;
    int c = off >> 6;
    int p = (off >> 3) & 7;
    int g = p ^ (c & 7);
    int k = kc * 64 + g * 8 + (off & 7);
    float4 L = *(const float4*)(psum_all + (size_t)b * S + k);
    #pragma unroll
    for (int t = 1; t < QSPLIT; ++t) {
        float4 Lt = *(const float4*)(psum_all + ((size_t)(t * BATCH + b)) * S + k);
        L.x += Lt.x; L.y += Lt.y; L.z += Lt.z; L.w += Lt.w;
    }
    ushort4 v = *(ushort4*)(Vimg + i);
    v.x = f2b(b2f(v.x) / L.x);
    v.y = f2b(b2f(v.y) / L.y);
    v.z = f2b(b2f(v.z) / L.z);
    v.w = f2b(b2f(v.w) / L.w);
    *(ushort4*)(Vimg + i) = v;
}

// ---------------- fused attention: out_part = exp2(Q K^T) @ Vhat, k-split ----------------
// grid (KSPLIT, S/128, BATCH), 256 thr. Q held in registers; QK^T computed TRANSPOSED
// (mfma(K,Q) -> S^T) so each lane holds 4 consecutive k per reg quad: pairs pack with
// v_cvt_pk_bf16_f32 into ds_write_b32 at XOR-swizzled [32][16] u32 per-wave P buffer
// (col' = c ^ (row&15), ~2-way banks both directions). 32-k K tiles (8 KB); V 64-chunk
// staged every other iteration via global_load_lds from the pre-swizzled image.
// LDS total 32 KB. launch_bounds(256,2): no reg spill (round-4 lesson).
__global__ __launch_bounds__(256, 2) void fused_attnv(
    const unsigned short* __restrict__ qh, const unsigned short* __restrict__ kh,
    const unsigned short* __restrict__ Vimg_all, unsigned short* __restrict__ parts)
{
    __shared__ unsigned short Ks[32 * 128];      // 8 KB, swizzled p = c ^ (r&15)
    __shared__ unsigned short Vls[128 * 64];     // 16 KB, image chunk (linear DMA)
    __shared__ unsigned int   Ps[4][32 * 16];    // 8 KB, per-wave P [32 q][16 u32] XOR-swz
    const int b = blockIdx.z;
    const unsigned short* Qm = qh + (size_t)b * S * 128;
    const unsigned short* Km = kh + (size_t)b * S * 128;
    const unsigned short* Vimg = Vimg_all + (((size_t)b * 64) << 13);
    unsigned short* Pout = parts + (size_t)blockIdx.x * ((size_t)MTOT * CNUM)
                                 + (size_t)b * S * CNUM;
    const int q0 = blockIdx.y * 128;
    const int kb0 = blockIdx.x * (S / KSPLIT);          // 512-k range
    const int kc0 = blockIdx.x * (S / KSPLIT / 64);     // first 64-k V chunk
    const int tid = threadIdx.x;
    const int w = tid >> 6, l = tid & 63;
    const int lm = l & 15, lq = l >> 4;
    const int row0 = q0 + w * 32;
    unsigned int* Pw = Ps[w];

    // Q fragments (B-operand layout), persistent across all k-tiles
    bf16x8 aq[2][4];
    #pragma unroll
    for (int i = 0; i < 2; ++i)
        #pragma unroll
        for (int ks = 0; ks < 4; ++ks)
            aq[i][ks] = *(const bf16x8*)(Qm + (size_t)(row0 + i * 16 + lm) * 128 + (ks * 4 + lq) * 8);

    f32x4 zero = {0.f, 0.f, 0.f, 0.f};
    f32x4 acco[2][8];
    #pragma unroll
    for (int i = 0; i < 2; ++i)
        #pragma unroll
        for (int j = 0; j < 8; ++j) acco[i][j] = zero;

    for (int kt = 0; kt < S / KSPLIT / 32; ++kt) {       // 16 iterations of 32 k
        const int kb = kb0 + kt * 32;
        __syncthreads();                                  // previous readers of Ks/Vls done
        // stage K tile [32][128] with read swizzle (reg staging)
        #pragma unroll
        for (int i2 = 0; i2 < 2; ++i2) {
            int cid = i2 * 256 + tid;
            int r = cid >> 4, c = cid & 15;
            int p = c ^ (r & 15);
            *(ulonglong2*)(Ks + r * 128 + p * 8) =
                *(const ulonglong2*)(Km + (size_t)(kb + r) * 128 + c * 8);
        }
        // stage Vhat 64-chunk every other iteration (pre-swizzled image, linear DMA)
        if ((kt & 1) == 0) {
            const unsigned short* src = Vimg + ((size_t)(kc0 + (kt >> 1)) << 13) + tid * 8;
            #pragma unroll
            for (int i2 = 0; i2 < 4; ++i2)
                gl_lds16(src + i2 * 2048, &Vls[(i2 * 256 + tid) * 8]);
        }
        __syncthreads();

        // transposed QK^T: accT[ki][qj], lane holds S[q=qj*16+lm][k=ki*16+lq*4+reg]
        f32x4 accT[2][2];
        #pragma unroll
        for (int ki = 0; ki < 2; ++ki)
            #pragma unroll
            for (int qj = 0; qj < 2; ++qj) accT[ki][qj] = zero;
        #pragma unroll
        for (int ks = 0; ks < 4; ++ks) {
            bf16x8 kfr[2];
            #pragma unroll
            for (int ki = 0; ki < 2; ++ki) {
                int n = ki * 16 + lm;
                int p = (ks * 4 + lq) ^ (n & 15);
                kfr[ki] = *(const bf16x8*)(Ks + n * 128 + p * 8);
            }
            #pragma unroll
            for (int ki = 0; ki < 2; ++ki)
                #pragma unroll
                for (int qj = 0; qj < 2; ++qj)
                    accT[ki][qj] = __builtin_amdgcn_mfma_f32_16x16x32_bf16(kfr[ki], aq[qj][ks], accT[ki][qj], 0, 0, 0);
        }

        // P = exp2 -> packed pairs -> Ps[row][c ^ (row&15)]
        #pragma unroll
        for (int qj = 0; qj < 2; ++qj) {
            unsigned int* pw = Pw + (qj * 16 + lm) * 16;
            #pragma unroll
            for (int ki = 0; ki < 2; ++ki)
                #pragma unroll
                for (int r2 = 0; r2 < 2; ++r2) {
                    float e0 = exp2f(accT[ki][qj][2 * r2]     * SCLOG2E);
                    float e1 = exp2f(accT[ki][qj][2 * r2 + 1] * SCLOG2E);
                    unsigned int pk;
                    asm("v_cvt_pk_bf16_f32 %0, %1, %2" : "=v"(pk) : "v"(e0), "v"(e1));
                    pw[(ki * 8 + lq * 2 + r2) ^ lm] = pk;
                }
        }

        // PV A-fragments from Ps (8 consecutive k = u32 cols lq*4..lq*4+3, XOR-swz)
        bf16x8 ap[2];
        #pragma unroll
        for (int i = 0; i < 2; ++i) {
            const unsigned int* pr = Pw + (i * 16 + lm) * 16;
            u32x4 uu = { pr[(lq * 4 + 0) ^ lm], pr[(lq * 4 + 1) ^ lm],
                         pr[(lq * 4 + 2) ^ lm], pr[(lq * 4 + 3) ^ lm] };
            ap[i] = __builtin_bit_cast(bf16x8, uu);
        }
        // PV: acco += P @ Vhat  (V half selected by kt parity)
        const int vh = (kt & 1) * 4;
        #pragma unroll
        for (int j = 0; j < 8; ++j) {
            int n = j * 16 + lm;
            bf16x8 bv = *(const bf16x8*)(Vls + n * 64 + (((vh + lq) ^ (n & 7)) << 3));
            acco[0][j] = __builtin_amdgcn_mfma_f32_16x16x32_bf16(ap[0], bv, acco[0][j], 0, 0, 0);
            acco[1][j] = __builtin_amdgcn_mfma_f32_16x16x32_bf16(ap[1], bv, acco[1][j], 0, 0, 0);
        }
    }

    #pragma unroll
    for (int i = 0; i < 2; ++i) {
        int rowb = row0 + i * 16 + lq * 4;
        #pragma unroll
        for (int j = 0; j < 8; ++j) {
            int col = j * 16 + lm;
            #pragma unroll
            for (int reg = 0; reg < 4; ++reg)
                Pout[(size_t)(rowb + reg) * CNUM + col] = f2b(acco[i][j][reg]);
        }
    }
}

// ---------------- reduce KSPLIT bf16 partials -> bf16 attouth ----------------
__global__ __launch_bounds__(256) void reduce8b(
    const ushort4* __restrict__ parts, ushort4* __restrict__ dst)
{
    size_t i = (size_t)blockIdx.x * 256 + threadIdx.x;
    const size_t stride = (size_t)MTOT * CNUM / 4;
    float sx = 0.f, sy = 0.f, sz = 0.f, sw = 0.f;
    #pragma unroll
    for (int p = 0; p < KSPLIT; ++p) {
        ushort4 v = parts[i + p * stride];
        sx += b2f(v.x); sy += b2f(v.y); sz += b2f(v.z); sw += b2f(v.w);
    }
    ushort4 o;
    o.x = f2b(sx); o.y = f2b(sy); o.z = f2b(sz); o.w = f2b(sw);
    dst[i] = o;
}

extern "C" void kernel_launch(void* const* d_in, const int* in_sizes, int n_in,
                              void* d_out, int out_size, void* d_ws, size_t ws_size,
                              hipStream_t stream)
{
    (void)in_sizes; (void)n_in; (void)out_size; (void)ws_size;
    const float* x    = (const float*)d_in[0];
    const float* ln1w = (const float*)d_in[1];
    const float* ln1b = (const float*)d_in[2];
    const float* wq   = (const float*)d_in[3];
    const float* bq   = (const float*)d_in[4];
    const float* wk   = (const float*)d_in[5];
    const float* bk   = (const float*)d_in[6];
    const float* wv   = (const float*)d_in[7];
    const float* bv   = (const float*)d_in[8];
    const float* wo   = (const float*)d_in[9];
    const float* bo   = (const float*)d_in[10];
    const float* ln2w = (const float*)d_in[11];
    const float* ln2b = (const float*)d_in[12];
    const float* w1   = (const float*)d_in[13];
    const float* b1   = (const float*)d_in[14];
    const float* w2   = (const float*)d_in[15];
    const float* b2   = (const float*)d_in[16];
    float* out = (float*)d_out;

    float* ws = (float*)d_ws;
    const size_t NSC = (size_t)MTOT * CNUM;            // 2,097,152
    float* t      = ws;
    float* y      = t + NSC;
    float* psum   = y + NSC;                           // [QSPLIT][B][S]
    unsigned short* parts = (unsigned short*)(psum + (size_t)QSPLIT * BATCH * S); // [KSPLIT][B][S][C]
    unsigned short* xlh = parts + (size_t)KSPLIT * NSC;
    unsigned short* qh  = xlh + NSC;
    unsigned short* kh  = qh + NSC;                    // V image must follow kh (epi 7 contiguity)
    unsigned short* Vt  = kh + NSC;                    // pre-swizzled V image
    unsigned short* attouth = Vt + NSC;
    unsigned short* zh  = attouth + NSC;
    unsigned short* hh  = zh + NSC;                    // [M,256] bf16
    unsigned short* wqkvh = hh + (size_t)MTOT * 256;
    unsigned short* woh = wqkvh + 3 * 16384;
    unsigned short* w1h = woh + 16384;                 // [256][128]
    unsigned short* w2h = w1h + 32768;                 // [128][256]
    float* bqkv = (float*)(w2h + 32768);               // [384]

    ln1_transpose<<<dim3(S / 64, BATCH), 256, 0, stream>>>(x, ln1w, ln1b, xlh, t);
    convw<<<dim3(128, 7), 256, 0, stream>>>(wq, wk, wv, wo, w1, w2, bq, bk, bv,
                                            wqkvh, woh, w1h, w2h, bqkv);

    // QKV: one launch, z = {q, k, v(image)}
    gemm_mfma<128, 7><<<dim3(1, MTOT / 64, 3), 256, 0, stream>>>(
        xlh, wqkvh, bqkv, nullptr, qh, nullptr, nullptr, nullptr, 128);

    colsum<<<dim3(S / 128, QSPLIT, BATCH), 256, 0, stream>>>(qh, kh, psum);
    vscale<<<dim3(CNUM * S / 4 / 256, 1, BATCH), 256, 0, stream>>>(Vt, psum);
    fused_attnv<<<dim3(KSPLIT, S / 128, BATCH), 256, 0, stream>>>(qh, kh, Vt, parts);
    reduce8b<<<NSC / 4 / 256, 256, 0, stream>>>((const ushort4*)parts, (ushort4*)attouth);

    // y = attouth @ wo + bo + t, fused LN2 -> zh (ln_rows eliminated)
    gemm_mfma<128, 3><<<dim3(1, MTOT / 64), 256, 0, stream>>>(
        attouth, woh, bo, t, y, zh, ln2w, ln2b, 128);
    // hh = gelu(zh @ w1 + b1) -> bf16
    gemm_mfma<128, 6><<<dim3(2, MTOT / 64), 256, 0, stream>>>(
        zh, w1h, b1, nullptr, hh, nullptr, nullptr, nullptr, 256);
    // out[b][c][s] = gelu(hh @ w2 + b2) + y   (fused transpose)
    gemm_mfma<256, 8><<<dim3(1, MTOT / 64), 256, 0, stream>>>(
        hh, w2h, b2, y, out, nullptr, nullptr, nullptr, 128);
}